// Round 11
// baseline (167.185 us; speedup 1.0000x reference)
//
#include <hip/hip_runtime.h>
#include <stdint.h>

#define M_DIM 16384
#define N_DIM 1024
#define K_DIM 1024

#define BM 128
#define BN 128
#define BK 64
#define NKT (K_DIM / BK)          // 16 K-steps
#define TILE_BYTES (BM * BK)      // 8192 B per (tile, K-step)

using i32x4 = __attribute__((ext_vector_type(4))) int;

__device__ __forceinline__ int pack4(int4 v) {
    return (v.x & 0xFF) | ((v.y & 0xFF) << 8) | ((v.z & 0xFF) << 16) | (v.w << 24);
}

// Swizzle: within each row's 64B (4 slots of 16B), canonical slot sigma is
// stored at s = sigma ^ ((row>>1)&3). Kills the 8-way ds_read_b128 conflict
// (R8 verified: SQ_LDS_BANK_CONFLICT == 0). For A it is applied at the LDS
// write (reg-staged); for B it is pre-applied in wqT (global_load_lds is
// linear-dest, rule #21).

// ---- pack w + corr: wqT[ntile][kt][512*16B] swizzled; corr[n] = bias - 3*colsum ----
__global__ __launch_bounds__(256) void pack_w_corr_kernel(const int* __restrict__ w,
                                                          const int* __restrict__ bias,
                                                          int8_t* __restrict__ wqT,
                                                          int* __restrict__ corr) {
    int n = blockIdx.x;
    int t = threadIdx.x;
    int4 v = ((const int4*)(w + (size_t)n * K_DIM))[t];
    int pk = pack4(v);
    int kt = t >> 4;                 // 64 ints per kt
    int sig = (t >> 2) & 3;          // canonical 16B slot within the row's 64B
    int d = t & 3;                   // dword within slot
    int rowin = n & 127;
    int ntile = n >> 7;
    int s = sig ^ ((rowin >> 1) & 3);
    ((int*)(wqT + ((size_t)(ntile * NKT + kt)) * TILE_BYTES))[(rowin * 4 + s) * 4 + d] = pk;

    int sum = v.x + v.y + v.z + v.w;
#pragma unroll
    for (int m = 1; m < 64; m <<= 1) sum += __shfl_xor(sum, m);
    __shared__ int partial[4];
    if ((t & 63) == 0) partial[t >> 6] = sum;
    __syncthreads();
    if (t == 0)
        corr[n] = bias[n] - 3 * (partial[0] + partial[1] + partial[2] + partial[3]);
}

// -------- fused GEMM: A packed in-register from x (int32), B via global_load_lds --------
// 128x128 tile, BK=64, 4 waves (2x2 of 64x64), mfma_i32_16x16x64_i8.
// Triple-buffered LDS (48 KB, 3 blocks/CU), ONE raw barrier per K-step,
// counted vmcnt only (never drain mid-loop): the R6 fusion resurrected with
// the R8/R9 barrier discipline (__syncthreads' vmcnt(0) drain was R6's bug).
__global__ __launch_bounds__(256) void gemm_fused_kernel(const int* __restrict__ X,
                                                         const int8_t* __restrict__ wqT,
                                                         const int* __restrict__ corr,
                                                         int* __restrict__ out) {
    __shared__ int8_t Asm[3][TILE_BYTES];
    __shared__ int8_t Bsm[3][TILE_BYTES];

    int bid = blockIdx.x;
    // XCD-bijective swizzle (nwg=1024 % 8 == 0): the 8 ntile-blocks of one
    // mtile are consecutive swz -> same XCD -> x panel L2-served after first touch.
    int swz = (bid & 7) * 128 + (bid >> 3);
    int mtile = swz >> 3;    // 0..127
    int ntile = swz & 7;     // 0..7
    int n0 = ntile * BN;
    int m0 = mtile * BM;

    int tid = threadIdx.x;
    int lane = tid & 63;
    int wave = tid >> 6;
    int wm = wave >> 1;
    int wn = wave & 1;
    int r16 = lane & 15;
    int krow = lane >> 4;                 // canonical k-slot
    int slot = krow ^ ((r16 >> 1) & 3);   // swizzled LDS slot

    i32x4 acc[4][4];
#pragma unroll
    for (int i = 0; i < 4; ++i)
#pragma unroll
        for (int j = 0; j < 4; ++j)
            acc[i][j] = (i32x4){0, 0, 0, 0};

    // A: thread handles 2 groups g; c = g*256+tid: row = c>>2, sig = c&3.
    // Loads 64B of one x row (4x int4, same cacheline), packs to one int4,
    // one ds_write_b128 at swizzled slot.
    int arow[2], asig[2];
    const int* Abase[2];
#pragma unroll
    for (int g = 0; g < 2; ++g) {
        int c = g * 256 + tid;
        arow[g] = c >> 2;
        asig[g] = c & 3;
        Abase[g] = X + (size_t)(m0 + arow[g]) * K_DIM + asig[g] * 16;
    }
    const int8_t* Bbase = wqT + (size_t)ntile * NKT * TILE_BYTES;

    int4 areg[2][4];   // [group][4 int4 of one 64B row segment]

#define ALD(kt)                                                                        \
    {                                                                                  \
        _Pragma("unroll") for (int g = 0; g < 2; ++g)                                  \
            _Pragma("unroll") for (int q = 0; q < 4; ++q)                              \
                areg[g][q] = *(const int4*)(Abase[g] + (size_t)(kt) * BK + q * 4);     \
    }

#define APW(buf)                                                                       \
    {                                                                                  \
        _Pragma("unroll") for (int g = 0; g < 2; ++g) {                                \
            i32x4 p;                                                                   \
            p[0] = pack4(areg[g][0]);                                                  \
            p[1] = pack4(areg[g][1]);                                                  \
            p[2] = pack4(areg[g][2]);                                                  \
            p[3] = pack4(areg[g][3]);                                                  \
            int su = asig[g] ^ ((arow[g] >> 1) & 3);                                   \
            *(i32x4*)(&Asm[buf][0] + ((size_t)arow[g] * 4 + su) * 16) = p;             \
        }                                                                              \
    }

#define BST(buf, kt)                                                                   \
    {                                                                                  \
        const int8_t* Bg = Bbase + (size_t)(kt) * TILE_BYTES;                          \
        _Pragma("unroll") for (int i = 0; i < 2; ++i) {                                \
            int f = i * 256 + tid;                                                     \
            __builtin_amdgcn_global_load_lds(                                          \
                (const __attribute__((address_space(1))) unsigned int*)(Bg + (size_t)f * 16), \
                (__attribute__((address_space(3))) unsigned int*)(&Bsm[buf][0] + f * 16),  \
                16, 0, 0);                                                             \
        }                                                                              \
    }

    // Prologue: invariant at each top-of-step barrier: A(kt+1) 8 + B(kt+1) 2 in flight.
    ALD(0); BST(0, 0);                                     // 10 outstanding
    asm volatile("s_waitcnt vmcnt(2)" ::: "memory");       // A0 regs ready
    APW(0);
    ALD(1); BST(1, 1);                                     // B0(2) + A1(8) + B1(2)
    asm volatile("s_waitcnt vmcnt(10) lgkmcnt(0)" ::: "memory");  // B0 landed, A0 writes retired
    __builtin_amdgcn_s_barrier();

#pragma unroll
    for (int kt = 0; kt < NKT; ++kt) {
        const int cur = kt % 3;

        // -------- compute(kt) --------
        i32x4 afr[4], bfr[4];
#pragma unroll
        for (int i = 0; i < 4; ++i) {
            afr[i] = *(const i32x4*)(&Asm[cur][0] + (size_t)(wm * 64 + i * 16 + r16) * 64 + slot * 16);
            bfr[i] = *(const i32x4*)(&Bsm[cur][0] + (size_t)(wn * 64 + i * 16 + r16) * 64 + slot * 16);
        }
#pragma unroll
        for (int i = 0; i < 4; ++i)
#pragma unroll
            for (int j = 0; j < 4; ++j)
                acc[i][j] = __builtin_amdgcn_mfma_i32_16x16x64_i8(afr[i], bfr[j], acc[i][j], 0, 0, 0);

        // -------- prepare buf kt+1, prefetch kt+2 --------
        if (kt <= NKT - 2) {
            asm volatile("s_waitcnt vmcnt(2)" ::: "memory");   // A(kt+1) regs ready
            APW((kt + 1) % 3);                                 // write-late (T14): loads had
                                                               // a full compute phase to land
            if (kt <= NKT - 3) {
                ALD(kt + 2); BST((kt + 2) % 3, kt + 2);
                asm volatile("s_waitcnt vmcnt(10) lgkmcnt(0)" ::: "memory"); // B(kt+1) landed
            } else {
                asm volatile("s_waitcnt vmcnt(0) lgkmcnt(0)" ::: "memory");
            }
            __builtin_amdgcn_s_barrier();                      // publish buf kt+1
        }
    }
#undef ALD
#undef APW
#undef BST

    // Epilogue: C/D layout col = lane&15, row = (lane>>4)*4 + reg; j innermost
    // so each output row's 256B segment is written temporally adjacent.
    int col16 = lane & 15;
    int rbase = (lane >> 4) * 4;
    int cr[4];
#pragma unroll
    for (int j = 0; j < 4; ++j) cr[j] = corr[n0 + wn * 64 + j * 16 + col16];
#pragma unroll
    for (int i = 0; i < 4; ++i) {
        int rrow = m0 + wm * 64 + i * 16 + rbase;
#pragma unroll
        for (int r = 0; r < 4; ++r) {
            size_t rowoff = (size_t)(rrow + r) * N_DIM;
#pragma unroll
            for (int j = 0; j < 4; ++j) {
                int t = acc[i][j][r] + cr[j];
                int res = ((t * 10) >> 10) - 5;       // floor((acc*10)/1024) + OUTPUT_ZP
                res = res < -128 ? -128 : (res > 127 ? 127 : res);
                out[rowoff + n0 + wn * 64 + j * 16 + col16] = res;
            }
        }
    }
}

extern "C" void kernel_launch(void* const* d_in, const int* in_sizes, int n_in,
                              void* d_out, int out_size, void* d_ws, size_t ws_size,
                              hipStream_t stream) {
    (void)in_sizes; (void)n_in; (void)out_size; (void)ws_size;
    const int* x    = (const int*)d_in[0];
    const int* w    = (const int*)d_in[1];
    const int* bias = (const int*)d_in[2];
    int* out = (int*)d_out;

    int8_t* wqT = (int8_t*)d_ws;                               // 1 MiB (tiled+swizzled)
    int* corr   = (int*)(wqT + (size_t)N_DIM * K_DIM);         // 4 KiB

    pack_w_corr_kernel<<<N_DIM, 256, 0, stream>>>(w, bias, wqT, corr);
    gemm_fused_kernel<<<(M_DIM / BM) * (N_DIM / BN), 256, 0, stream>>>(x, wqT, corr, out);
}